// Round 3
// baseline (737.237 us; speedup 1.0000x reference)
//
#include <hip/hip_runtime.h>
#include <hip/hip_bf16.h>
#include <cstdint>
#include <cstddef>

#define NN 50000
#define NE 800000

typedef __attribute__((ext_vector_type(8))) short bf16x8;
typedef __attribute__((ext_vector_type(4))) float f32x4;

static __device__ __forceinline__ unsigned short f2bf_u(float f) {
    __hip_bfloat16 h = __float2bfloat16(f);
    return *reinterpret_cast<unsigned short*>(&h);
}
static __device__ __forceinline__ float bfu2f(unsigned short u) {
    __hip_bfloat16 h = *reinterpret_cast<__hip_bfloat16*>(&u);
    return __bfloat162float(h);
}

// ---------------- degree / normalization ----------------

__global__ void k_init_deg(float* deg, int n) {
    int i = blockIdx.x * blockDim.x + threadIdx.x;
    if (i < n) deg[i] = 1.0f;
}

__global__ void k_edge_pass1(const int* __restrict__ ecol, const float* __restrict__ eval_,
                             float* __restrict__ deg, int* __restrict__ cnt, int e) {
    int i = blockIdx.x * blockDim.x + threadIdx.x;
    if (i < e) {
        int d = ecol[i];
        atomicAdd(&deg[d], eval_[i]);
        atomicAdd(&cnt[d], 1);
    }
}

__global__ void k_dinv(const float* __restrict__ deg, float* __restrict__ dinv, int n) {
    int i = blockIdx.x * blockDim.x + threadIdx.x;
    if (i < n) {
        float d = deg[i];
        dinv[i] = d > 0.f ? rsqrtf(d) : 0.f;
    }
}

// ---------------- multi-block exclusive scan ----------------

__global__ void k_scan_blk(const int* __restrict__ cnt, int* __restrict__ ex,
                           int* __restrict__ bsum, int n) {
    int tid = threadIdx.x;
    int i = blockIdx.x * 256 + tid;
    int v = (i < n) ? cnt[i] : 0;
    int lane = tid & 63, w = tid >> 6;
    int incl = v;
#pragma unroll
    for (int d = 1; d < 64; d <<= 1) {
        int t = __shfl_up(incl, d);
        if (lane >= d) incl += t;
    }
    __shared__ int wsum[4];
    if (lane == 63) wsum[w] = incl;
    __syncthreads();
    int woff = 0;
    for (int j = 0; j < w; ++j) woff += wsum[j];
    if (i < n) ex[i] = woff + incl - v;
    if (tid == 255) bsum[blockIdx.x] = woff + incl;
}

__global__ void k_scan_top(int* __restrict__ bsum, int nb) {
    int tid = threadIdx.x;
    int v = (tid < nb) ? bsum[tid] : 0;
    int lane = tid & 63, w = tid >> 6;
    int incl = v;
#pragma unroll
    for (int d = 1; d < 64; d <<= 1) {
        int t = __shfl_up(incl, d);
        if (lane >= d) incl += t;
    }
    __shared__ int wsum[4];
    if (lane == 63) wsum[w] = incl;
    __syncthreads();
    int woff = 0;
    for (int j = 0; j < w; ++j) woff += wsum[j];
    if (tid < nb) bsum[tid] = woff + incl - v;
}

__global__ void k_scan_add(const int* __restrict__ ex, const int* __restrict__ boff,
                           int* __restrict__ rowptr, int* __restrict__ cur, int n, int total) {
    int i = blockIdx.x * 256 + threadIdx.x;
    if (i < n) {
        int v = ex[i] + boff[blockIdx.x];
        rowptr[i] = v;
        cur[i] = v;
    }
    if (i == 0) rowptr[n] = total;
}

// ---------------- CSR scatter ----------------

__global__ void k_scatter(const int* __restrict__ erow, const int* __restrict__ ecol,
                          const float* __restrict__ eval_, const float* __restrict__ dinv,
                          int* __restrict__ cur, int* __restrict__ esrc,
                          float* __restrict__ ew, int e) {
    int i = blockIdx.x * blockDim.x + threadIdx.x;
    if (i < e) {
        int d = ecol[i], s = erow[i];
        int pos = atomicAdd(&cur[d], 1);
        esrc[pos] = s;
        ew[pos] = dinv[d] * eval_[i] * dinv[s];
    }
}

// ---------------- sparse aggregation: gather bf16 H, fp32 accumulate/out ----------
// out[i,:] = dinv[i]^2 * H[i,:] + sum_j ew[j] * H[esrc[j],:]  (+bias, opt relu)
// DIM/2 threads per row (each thread owns 2 cols via packed bf16x2).
template<int DIM, bool RELU>
__global__ __launch_bounds__(256) void k_agg(const unsigned short* __restrict__ H,
                      const int* __restrict__ rowptr,
                      const int* __restrict__ esrc, const float* __restrict__ ew,
                      const float* __restrict__ dinv, const float* __restrict__ bias,
                      float* __restrict__ out) {
    constexpr int TPR = DIM / 2;
    constexpr int RPB = 256 / TPR;
    int tid = threadIdx.x;
    int row = blockIdx.x * RPB + tid / TPR;
    int t = tid % TPR;
    if (row >= NN) return;
    const unsigned* Hu = reinterpret_cast<const unsigned*>(H);
    float di = dinv[row];
    float dd = di * di;
    unsigned u = Hu[(size_t)row * TPR + t];
    float ax = dd * __uint_as_float(u << 16);
    float ay = dd * __uint_as_float(u & 0xffff0000u);
    int beg = rowptr[row], end = rowptr[row + 1];
    for (int e = beg; e < end; ++e) {
        int s = esrc[e];
        float w = ew[e];
        unsigned v = Hu[(size_t)s * TPR + t];
        ax += w * __uint_as_float(v << 16);
        ay += w * __uint_as_float(v & 0xffff0000u);
    }
    float2 bv = reinterpret_cast<const float2*>(bias)[t];
    ax += bv.x;
    ay += bv.y;
    if (RELU) { ax = fmaxf(ax, 0.f); ay = fmaxf(ay, 0.f); }
    reinterpret_cast<float2*>(out)[(size_t)row * TPR + t] = make_float2(ax, ay);
}

// ---------------- weight pre-split into fragment-ordered hi/lo bf16 ----------------
// layout: [kb=K/32][nb=M/16] chunks of 512 shorts: [kg=4][c=16][kj=8]
__global__ void k_wsplit(const float* __restrict__ W, unsigned short* __restrict__ wh,
                         unsigned short* __restrict__ wl, int K, int M) {
    int idx = blockIdx.x * blockDim.x + threadIdx.x;
    if (idx >= K * M) return;
    int k = idx / M, m = idx % M;
    float w = W[idx];
    unsigned short h = f2bf_u(w);
    float hf = bfu2f(h);
    unsigned short lo = f2bf_u(w - hf);
    int kb = k >> 5, kg = (k & 31) >> 3, kj = k & 7;
    int nb = m >> 4, c = m & 15;
    int off = (kb * (M >> 4) + nb) * 512 + kg * 128 + c * 8 + kj;
    wh[off] = h;
    wl[off] = lo;
}

// ---------------- MFMA GEMM: C = A(fp32) @ W (split-bf16, 3-pass) ----------------
// BM x BN tile, BK=32, wave tile 64x64. OBF: write C as bf16.
template<int BM, int BN, bool RELU, bool OBF>
__global__ __launch_bounds__((BM / 64) * (BN / 64) * 64)
void k_mm(const float* __restrict__ A, const unsigned short* __restrict__ wh,
          const unsigned short* __restrict__ wl, const float* __restrict__ bias,
          void* __restrict__ Cout, int nrows, int K, int M) {
    constexpr int T = (BM / 64) * (BN / 64) * 64;
    constexpr int WN = BN / 64;
    constexpr int QI = BM * 8 / T;
    __shared__ unsigned short Ah[BM * 32], Al[BM * 32], Bh[BN * 32], Bl[BN * 32];
    int tid = threadIdx.x;
    int l = tid & 63;
    int wid = tid >> 6;
    int wr = wid / WN, wc = wid % WN;
    int bm = blockIdx.x * BM, bn = blockIdx.y * BN;
    int nb0 = bn >> 4;
    f32x4 acc[4][4] = {};
    int fo = (l >> 4) * 128 + (l & 15) * 8;

    for (int k0 = 0; k0 < K; k0 += 32) {
        int kb = k0 >> 5;
#pragma unroll
        for (int q = 0; q < QI; ++q) {
            int t2 = tid + q * T;
            int row = t2 >> 3, kq = t2 & 7;
            int grow = bm + row;
            float4 av = make_float4(0.f, 0.f, 0.f, 0.f);
            if (grow < nrows)
                av = *reinterpret_cast<const float4*>(&A[(size_t)grow * K + k0 + kq * 4]);
            unsigned short h0 = f2bf_u(av.x), h1 = f2bf_u(av.y),
                           h2 = f2bf_u(av.z), h3 = f2bf_u(av.w);
            uint2 hp, lp;
            hp.x = (unsigned)h0 | ((unsigned)h1 << 16);
            hp.y = (unsigned)h2 | ((unsigned)h3 << 16);
            lp.x = (unsigned)f2bf_u(av.x - bfu2f(h0)) | ((unsigned)f2bf_u(av.y - bfu2f(h1)) << 16);
            lp.y = (unsigned)f2bf_u(av.z - bfu2f(h2)) | ((unsigned)f2bf_u(av.w - bfu2f(h3)) << 16);
            int off = (row >> 4) * 512 + (kq >> 1) * 128 + (row & 15) * 8 + (kq & 1) * 4;
            *reinterpret_cast<uint2*>(&Ah[off]) = hp;
            *reinterpret_cast<uint2*>(&Al[off]) = lp;
        }
        const int4* sh = reinterpret_cast<const int4*>(wh) + (size_t)(kb * (M >> 4) + nb0) * 64;
        const int4* sl = reinterpret_cast<const int4*>(wl) + (size_t)(kb * (M >> 4) + nb0) * 64;
        for (int u = tid; u < BN * 4; u += T) {
            *reinterpret_cast<int4*>(&Bh[u * 8]) = sh[u];
            *reinterpret_cast<int4*>(&Bl[u * 8]) = sl[u];
        }
        __syncthreads();
        bf16x8 ah[4], al4[4], bh4[4], bl4[4];
#pragma unroll
        for (int i = 0; i < 4; ++i) {
            ah[i]  = *reinterpret_cast<const bf16x8*>(&Ah[(wr * 4 + i) * 512 + fo]);
            al4[i] = *reinterpret_cast<const bf16x8*>(&Al[(wr * 4 + i) * 512 + fo]);
        }
#pragma unroll
        for (int j = 0; j < 4; ++j) {
            bh4[j] = *reinterpret_cast<const bf16x8*>(&Bh[(wc * 4 + j) * 512 + fo]);
            bl4[j] = *reinterpret_cast<const bf16x8*>(&Bl[(wc * 4 + j) * 512 + fo]);
        }
#pragma unroll
        for (int i = 0; i < 4; ++i)
#pragma unroll
            for (int j = 0; j < 4; ++j) {
                acc[i][j] = __builtin_amdgcn_mfma_f32_16x16x32_bf16(ah[i],  bh4[j], acc[i][j], 0, 0, 0);
                acc[i][j] = __builtin_amdgcn_mfma_f32_16x16x32_bf16(ah[i],  bl4[j], acc[i][j], 0, 0, 0);
                acc[i][j] = __builtin_amdgcn_mfma_f32_16x16x32_bf16(al4[i], bh4[j], acc[i][j], 0, 0, 0);
            }
        __syncthreads();
    }
#pragma unroll
    for (int j = 0; j < 4; ++j) {
        int col = bn + wc * 64 + j * 16 + (l & 15);
        float bv = bias ? bias[col] : 0.f;
#pragma unroll
        for (int i = 0; i < 4; ++i) {
            int row0 = bm + wr * 64 + i * 16 + (l >> 4) * 4;
#pragma unroll
            for (int r = 0; r < 4; ++r) {
                int row = row0 + r;
                if (row < nrows) {
                    float v = acc[i][j][r] + bv;
                    if (RELU) v = fmaxf(v, 0.f);
                    if (OBF)
                        ((unsigned short*)Cout)[(size_t)row * M + col] = f2bf_u(v);
                    else
                        ((float*)Cout)[(size_t)row * M + col] = v;
                }
            }
        }
    }
}

// ---------------- launch ----------------

extern "C" void kernel_launch(void* const* d_in, const int* in_sizes, int n_in,
                              void* d_out, int out_size, void* d_ws, size_t ws_size,
                              hipStream_t stream) {
    const float* x        = (const float*)d_in[0];
    const int*   edge_row = (const int*)d_in[1];
    const int*   edge_col = (const int*)d_in[2];
    const float* edge_val = (const float*)d_in[3];
    const float* W1  = (const float*)d_in[4];
    const float* b1  = (const float*)d_in[5];
    const float* W2  = (const float*)d_in[6];
    const float* b2  = (const float*)d_in[7];
    const float* W3  = (const float*)d_in[8];
    const float* b3  = (const float*)d_in[9];
    const float* P1  = (const float*)d_in[10];
    const float* pb1 = (const float*)d_in[11];
    const float* P2  = (const float*)d_in[12];
    const float* pb2 = (const float*)d_in[13];

    const int N = NN, E = NE;
    const int NB = (N + 255) / 256;

    uintptr_t p = (uintptr_t)d_ws;
    auto alloc = [&](size_t bytes) -> void* {
        void* r = (void*)p;
        p += (bytes + 255) & ~(size_t)255;
        return r;
    };
    float* deg    = (float*)alloc((size_t)N * 4);
    float* dinv   = (float*)alloc((size_t)N * 4);
    int*   cnt    = (int*)alloc((size_t)N * 4);
    int*   rowptr = (int*)alloc((size_t)(N + 1) * 4);
    int*   cur    = (int*)alloc((size_t)N * 4);
    int*   bsum   = (int*)alloc(256 * 4);
    int*   esrc   = (int*)alloc((size_t)E * 4);
    float* ew     = (float*)alloc((size_t)E * 4);
    unsigned short* Hbf = (unsigned short*)alloc((size_t)N * 256 * 2);  // bf16 pre-agg H
    float* bufB   = (float*)alloc((size_t)N * 256 * 4);                 // fp32 agg out
    float* bufT   = (float*)alloc((size_t)N * 128 * 4);                 // head intermediate
    unsigned short* wf1h = (unsigned short*)alloc(65536 * 2);
    unsigned short* wf1l = (unsigned short*)alloc(65536 * 2);
    unsigned short* wf2h = (unsigned short*)alloc(65536 * 2);
    unsigned short* wf2l = (unsigned short*)alloc(65536 * 2);
    unsigned short* wf3h = (unsigned short*)alloc(32768 * 2);
    unsigned short* wf3l = (unsigned short*)alloc(32768 * 2);
    unsigned short* p1h  = (unsigned short*)alloc(16384 * 2);
    unsigned short* p1l  = (unsigned short*)alloc(16384 * 2);
    unsigned short* p2h  = (unsigned short*)alloc(16384 * 2);
    unsigned short* p2l  = (unsigned short*)alloc(16384 * 2);

    float* emb = (float*)d_out;
    float* z   = (float*)d_out + (size_t)N * 128;

    dim3 b256(256);
    dim3 gN(NB);
    dim3 gE((E + 255) / 256);

    k_wsplit<<<dim3(256), b256, 0, stream>>>(W1, wf1h, wf1l, 256, 256);
    k_wsplit<<<dim3(256), b256, 0, stream>>>(W2, wf2h, wf2l, 256, 256);
    k_wsplit<<<dim3(128), b256, 0, stream>>>(W3, wf3h, wf3l, 256, 128);
    k_wsplit<<<dim3(64),  b256, 0, stream>>>(P1, p1h, p1l, 128, 128);
    k_wsplit<<<dim3(64),  b256, 0, stream>>>(P2, p2h, p2l, 128, 128);

    hipMemsetAsync(cnt, 0, (size_t)N * 4, stream);
    k_init_deg<<<gN, b256, 0, stream>>>(deg, N);
    k_edge_pass1<<<gE, b256, 0, stream>>>(edge_col, edge_val, deg, cnt, E);
    k_dinv<<<gN, b256, 0, stream>>>(deg, dinv, N);
    k_scan_blk<<<gN, b256, 0, stream>>>(cnt, cnt, bsum, N);
    k_scan_top<<<dim3(1), b256, 0, stream>>>(bsum, NB);
    k_scan_add<<<gN, b256, 0, stream>>>(cnt, bsum, rowptr, cur, N, E);
    k_scatter<<<gE, b256, 0, stream>>>(edge_row, edge_col, edge_val, dinv, cur, esrc, ew, E);

    const int gm64  = (N + 63) / 64;    // 782
    const int gm128 = (N + 127) / 128;  // 391
    const int gagg256 = (N + 1) / 2;    // 2 rows/block
    const int gagg128 = (N + 3) / 4;    // 4 rows/block

    // layer 1: H = x @ W1 (bf16) ; bufB = relu(agg(H) + b1)
    k_mm<64, 256, false, true><<<dim3(gm64, 1), dim3(256), 0, stream>>>(x, wf1h, wf1l, nullptr, Hbf, N, 256, 256);
    k_agg<256, true><<<dim3(gagg256), b256, 0, stream>>>(Hbf, rowptr, esrc, ew, dinv, b1, bufB);
    // layer 2
    k_mm<64, 256, false, true><<<dim3(gm64, 1), dim3(256), 0, stream>>>(bufB, wf2h, wf2l, nullptr, Hbf, N, 256, 256);
    k_agg<256, true><<<dim3(gagg256), b256, 0, stream>>>(Hbf, rowptr, esrc, ew, dinv, b2, bufB);
    // layer 3
    k_mm<128, 128, false, true><<<dim3(gm128, 1), dim3(256), 0, stream>>>(bufB, wf3h, wf3l, nullptr, Hbf, N, 256, 128);
    k_agg<128, false><<<dim3(gagg128), b256, 0, stream>>>(Hbf, rowptr, esrc, ew, dinv, b3, emb);
    // head
    k_mm<64, 128, true,  false><<<dim3(gm64, 1), dim3(128), 0, stream>>>(emb, p1h, p1l, pb1, bufT, N, 128, 128);
    k_mm<64, 128, false, false><<<dim3(gm64, 1), dim3(128), 0, stream>>>(bufT, p2h, p2l, pb2, z, N, 128, 128);
}

// Round 4
// 497.194 us; speedup vs baseline: 1.4828x; 1.4828x over previous
//
#include <hip/hip_runtime.h>
#include <hip/hip_bf16.h>
#include <cstdint>
#include <cstddef>

#define NN 50000
#define NE 800000

typedef __attribute__((ext_vector_type(8))) short bf16x8;
typedef __attribute__((ext_vector_type(4))) float f32x4;

static __device__ __forceinline__ unsigned short f2bf_u(float f) {
    __hip_bfloat16 h = __float2bfloat16(f);
    return *reinterpret_cast<unsigned short*>(&h);
}
static __device__ __forceinline__ float bfu2f(unsigned short u) {
    __hip_bfloat16 h = *reinterpret_cast<__hip_bfloat16*>(&u);
    return __bfloat162float(h);
}

// ---------------- degree / normalization ----------------

__global__ void k_init_deg(float* deg, int n) {
    int i = blockIdx.x * blockDim.x + threadIdx.x;
    if (i < n) deg[i] = 1.0f;
}

__global__ void k_edge_pass1(const int* __restrict__ ecol, const float* __restrict__ eval_,
                             float* __restrict__ deg, int* __restrict__ cnt, int e) {
    int i = blockIdx.x * blockDim.x + threadIdx.x;
    if (i < e) {
        int d = ecol[i];
        atomicAdd(&deg[d], eval_[i]);
        atomicAdd(&cnt[d], 1);
    }
}

__global__ void k_dinv(const float* __restrict__ deg, float* __restrict__ dinv, int n) {
    int i = blockIdx.x * blockDim.x + threadIdx.x;
    if (i < n) {
        float d = deg[i];
        dinv[i] = d > 0.f ? rsqrtf(d) : 0.f;
    }
}

// ---------------- multi-block exclusive scan ----------------

__global__ void k_scan_blk(const int* __restrict__ cnt, int* __restrict__ ex,
                           int* __restrict__ bsum, int n) {
    int tid = threadIdx.x;
    int i = blockIdx.x * 256 + tid;
    int v = (i < n) ? cnt[i] : 0;
    int lane = tid & 63, w = tid >> 6;
    int incl = v;
#pragma unroll
    for (int d = 1; d < 64; d <<= 1) {
        int t = __shfl_up(incl, d);
        if (lane >= d) incl += t;
    }
    __shared__ int wsum[4];
    if (lane == 63) wsum[w] = incl;
    __syncthreads();
    int woff = 0;
    for (int j = 0; j < w; ++j) woff += wsum[j];
    if (i < n) ex[i] = woff + incl - v;
    if (tid == 255) bsum[blockIdx.x] = woff + incl;
}

__global__ void k_scan_top(int* __restrict__ bsum, int nb) {
    int tid = threadIdx.x;
    int v = (tid < nb) ? bsum[tid] : 0;
    int lane = tid & 63, w = tid >> 6;
    int incl = v;
#pragma unroll
    for (int d = 1; d < 64; d <<= 1) {
        int t = __shfl_up(incl, d);
        if (lane >= d) incl += t;
    }
    __shared__ int wsum[4];
    if (lane == 63) wsum[w] = incl;
    __syncthreads();
    int woff = 0;
    for (int j = 0; j < w; ++j) woff += wsum[j];
    if (tid < nb) bsum[tid] = woff + incl - v;
}

__global__ void k_scan_add(const int* __restrict__ ex, const int* __restrict__ boff,
                           int* __restrict__ rowptr, int* __restrict__ cur, int n, int total) {
    int i = blockIdx.x * 256 + threadIdx.x;
    if (i < n) {
        int v = ex[i] + boff[blockIdx.x];
        rowptr[i] = v;
        cur[i] = v;
    }
    if (i == 0) rowptr[n] = total;
}

// ---------------- CSR scatter (packed src+weight) ----------------

__global__ void k_scatter(const int* __restrict__ erow, const int* __restrict__ ecol,
                          const float* __restrict__ eval_, const float* __restrict__ dinv,
                          int* __restrict__ cur, int2* __restrict__ epk, int e) {
    int i = blockIdx.x * blockDim.x + threadIdx.x;
    if (i < e) {
        int d = ecol[i], s = erow[i];
        int pos = atomicAdd(&cur[d], 1);
        float w = dinv[d] * eval_[i] * dinv[s];
        epk[pos] = make_int2(s, __float_as_int(w));
    }
}

// ---------------- sparse aggregation: wave-per-row, shfl indices, 4x MLP ------
// out[i,:] = dinv[i]^2 * H[i,:] + sum_j w[j] * H[src[j],:]  (+bias, opt relu)
// H bf16 [N][DIM]; out fp32. 64 lanes/row, 4 rows/block, no barriers.
template<int DIM, bool RELU>
__global__ __launch_bounds__(256) void k_agg(const unsigned short* __restrict__ H,
                      const int* __restrict__ rowptr, const int2* __restrict__ epk,
                      const float* __restrict__ dinv, const float* __restrict__ bias,
                      float* __restrict__ out) {
    constexpr int WU = DIM / 128;  // uints per lane: 2 (DIM=256) or 1 (DIM=128)
    int lane = threadIdx.x & 63;
    int row = blockIdx.x * 4 + (threadIdx.x >> 6);
    if (row >= NN) return;

    const uint2* H2 = reinterpret_cast<const uint2*>(H);
    const unsigned* H1 = reinterpret_cast<const unsigned*>(H);

    auto loadrow = [&](int r, unsigned* v) {
        if constexpr (WU == 2) {
            uint2 t = H2[(size_t)r * 64 + lane];
            v[0] = t.x; v[1] = t.y;
        } else {
            v[0] = H1[(size_t)r * 64 + lane];
        }
    };

    float acc[WU * 2];
    {
        float di = dinv[row];
        float dd = di * di;
        unsigned sv[WU];
        loadrow(row, sv);
#pragma unroll
        for (int w2 = 0; w2 < WU; ++w2) {
            acc[w2 * 2 + 0] = dd * __uint_as_float(sv[w2] << 16);
            acc[w2 * 2 + 1] = dd * __uint_as_float(sv[w2] & 0xffff0000u);
        }
    }

    auto accum = [&](const unsigned* v, float wt) {
#pragma unroll
        for (int w2 = 0; w2 < WU; ++w2) {
            acc[w2 * 2 + 0] += wt * __uint_as_float(v[w2] << 16);
            acc[w2 * 2 + 1] += wt * __uint_as_float(v[w2] & 0xffff0000u);
        }
    };

    int beg = rowptr[row], end = rowptr[row + 1];
    for (int c = beg; c < end; c += 64) {
        int m = min(64, end - c);
        int2 pk = make_int2(0, 0);
        if (c + lane < end) pk = epk[c + lane];
        int j = 0;
        for (; j + 4 <= m; j += 4) {
            int s0 = __shfl(pk.x, j + 0), s1 = __shfl(pk.x, j + 1);
            int s2 = __shfl(pk.x, j + 2), s3 = __shfl(pk.x, j + 3);
            float w0 = __int_as_float(__shfl(pk.y, j + 0));
            float w1 = __int_as_float(__shfl(pk.y, j + 1));
            float w2 = __int_as_float(__shfl(pk.y, j + 2));
            float w3 = __int_as_float(__shfl(pk.y, j + 3));
            unsigned g0[WU], g1[WU], g2[WU], g3[WU];
            loadrow(s0, g0);
            loadrow(s1, g1);
            loadrow(s2, g2);
            loadrow(s3, g3);
            accum(g0, w0);
            accum(g1, w1);
            accum(g2, w2);
            accum(g3, w3);
        }
        for (; j < m; ++j) {
            int s = __shfl(pk.x, j);
            float wt = __int_as_float(__shfl(pk.y, j));
            unsigned g[WU];
            loadrow(s, g);
            accum(g, wt);
        }
    }

    if constexpr (WU == 2) {
        float4 b4 = reinterpret_cast<const float4*>(bias)[lane];
        float4 o;
        o.x = acc[0] + b4.x; o.y = acc[1] + b4.y;
        o.z = acc[2] + b4.z; o.w = acc[3] + b4.w;
        if (RELU) {
            o.x = fmaxf(o.x, 0.f); o.y = fmaxf(o.y, 0.f);
            o.z = fmaxf(o.z, 0.f); o.w = fmaxf(o.w, 0.f);
        }
        reinterpret_cast<float4*>(out)[(size_t)row * 64 + lane] = o;
    } else {
        float2 b2 = reinterpret_cast<const float2*>(bias)[lane];
        float2 o;
        o.x = acc[0] + b2.x; o.y = acc[1] + b2.y;
        if (RELU) { o.x = fmaxf(o.x, 0.f); o.y = fmaxf(o.y, 0.f); }
        reinterpret_cast<float2*>(out)[(size_t)row * 64 + lane] = o;
    }
}

// ---------------- weight pre-split into fragment-ordered hi/lo bf16 ----------------
// layout: [kb=K/32][nb=M/16] chunks of 512 shorts: [kg=4][c=16][kj=8]
__global__ void k_wsplit(const float* __restrict__ W, unsigned short* __restrict__ wh,
                         unsigned short* __restrict__ wl, int K, int M) {
    int idx = blockIdx.x * blockDim.x + threadIdx.x;
    if (idx >= K * M) return;
    int k = idx / M, m = idx % M;
    float w = W[idx];
    unsigned short h = f2bf_u(w);
    float hf = bfu2f(h);
    unsigned short lo = f2bf_u(w - hf);
    int kb = k >> 5, kg = (k & 31) >> 3, kj = k & 7;
    int nb = m >> 4, c = m & 15;
    int off = (kb * (M >> 4) + nb) * 512 + kg * 128 + c * 8 + kj;
    wh[off] = h;
    wl[off] = lo;
}

// ---------------- MFMA GEMM: C = A(fp32) @ W (split-bf16, 3-pass) ----------------
template<int BM, int BN, bool RELU, bool OBF>
__global__ __launch_bounds__((BM / 64) * (BN / 64) * 64)
void k_mm(const float* __restrict__ A, const unsigned short* __restrict__ wh,
          const unsigned short* __restrict__ wl, const float* __restrict__ bias,
          void* __restrict__ Cout, int nrows, int K, int M) {
    constexpr int T = (BM / 64) * (BN / 64) * 64;
    constexpr int WN = BN / 64;
    constexpr int QI = BM * 8 / T;
    __shared__ unsigned short Ah[BM * 32], Al[BM * 32], Bh[BN * 32], Bl[BN * 32];
    int tid = threadIdx.x;
    int l = tid & 63;
    int wid = tid >> 6;
    int wr = wid / WN, wc = wid % WN;
    int bm = blockIdx.x * BM, bn = blockIdx.y * BN;
    int nb0 = bn >> 4;
    f32x4 acc[4][4] = {};
    int fo = (l >> 4) * 128 + (l & 15) * 8;

    for (int k0 = 0; k0 < K; k0 += 32) {
        int kb = k0 >> 5;
#pragma unroll
        for (int q = 0; q < QI; ++q) {
            int t2 = tid + q * T;
            int row = t2 >> 3, kq = t2 & 7;
            int grow = bm + row;
            float4 av = make_float4(0.f, 0.f, 0.f, 0.f);
            if (grow < nrows)
                av = *reinterpret_cast<const float4*>(&A[(size_t)grow * K + k0 + kq * 4]);
            unsigned short h0 = f2bf_u(av.x), h1 = f2bf_u(av.y),
                           h2 = f2bf_u(av.z), h3 = f2bf_u(av.w);
            uint2 hp, lp;
            hp.x = (unsigned)h0 | ((unsigned)h1 << 16);
            hp.y = (unsigned)h2 | ((unsigned)h3 << 16);
            lp.x = (unsigned)f2bf_u(av.x - bfu2f(h0)) | ((unsigned)f2bf_u(av.y - bfu2f(h1)) << 16);
            lp.y = (unsigned)f2bf_u(av.z - bfu2f(h2)) | ((unsigned)f2bf_u(av.w - bfu2f(h3)) << 16);
            int off = (row >> 4) * 512 + (kq >> 1) * 128 + (row & 15) * 8 + (kq & 1) * 4;
            *reinterpret_cast<uint2*>(&Ah[off]) = hp;
            *reinterpret_cast<uint2*>(&Al[off]) = lp;
        }
        const int4* sh = reinterpret_cast<const int4*>(wh) + (size_t)(kb * (M >> 4) + nb0) * 64;
        const int4* sl = reinterpret_cast<const int4*>(wl) + (size_t)(kb * (M >> 4) + nb0) * 64;
        for (int u = tid; u < BN * 4; u += T) {
            *reinterpret_cast<int4*>(&Bh[u * 8]) = sh[u];
            *reinterpret_cast<int4*>(&Bl[u * 8]) = sl[u];
        }
        __syncthreads();
        bf16x8 ah[4], al4[4], bh4[4], bl4[4];
#pragma unroll
        for (int i = 0; i < 4; ++i) {
            ah[i]  = *reinterpret_cast<const bf16x8*>(&Ah[(wr * 4 + i) * 512 + fo]);
            al4[i] = *reinterpret_cast<const bf16x8*>(&Al[(wr * 4 + i) * 512 + fo]);
        }
#pragma unroll
        for (int j = 0; j < 4; ++j) {
            bh4[j] = *reinterpret_cast<const bf16x8*>(&Bh[(wc * 4 + j) * 512 + fo]);
            bl4[j] = *reinterpret_cast<const bf16x8*>(&Bl[(wc * 4 + j) * 512 + fo]);
        }
#pragma unroll
        for (int i = 0; i < 4; ++i)
#pragma unroll
            for (int j = 0; j < 4; ++j) {
                acc[i][j] = __builtin_amdgcn_mfma_f32_16x16x32_bf16(ah[i],  bh4[j], acc[i][j], 0, 0, 0);
                acc[i][j] = __builtin_amdgcn_mfma_f32_16x16x32_bf16(ah[i],  bl4[j], acc[i][j], 0, 0, 0);
                acc[i][j] = __builtin_amdgcn_mfma_f32_16x16x32_bf16(al4[i], bh4[j], acc[i][j], 0, 0, 0);
            }
        __syncthreads();
    }
#pragma unroll
    for (int j = 0; j < 4; ++j) {
        int col = bn + wc * 64 + j * 16 + (l & 15);
        float bv = bias ? bias[col] : 0.f;
#pragma unroll
        for (int i = 0; i < 4; ++i) {
            int row0 = bm + wr * 64 + i * 16 + (l >> 4) * 4;
#pragma unroll
            for (int r = 0; r < 4; ++r) {
                int row = row0 + r;
                if (row < nrows) {
                    float v = acc[i][j][r] + bv;
                    if (RELU) v = fmaxf(v, 0.f);
                    if (OBF)
                        ((unsigned short*)Cout)[(size_t)row * M + col] = f2bf_u(v);
                    else
                        ((float*)Cout)[(size_t)row * M + col] = v;
                }
            }
        }
    }
}

// ---------------- launch ----------------

extern "C" void kernel_launch(void* const* d_in, const int* in_sizes, int n_in,
                              void* d_out, int out_size, void* d_ws, size_t ws_size,
                              hipStream_t stream) {
    const float* x        = (const float*)d_in[0];
    const int*   edge_row = (const int*)d_in[1];
    const int*   edge_col = (const int*)d_in[2];
    const float* edge_val = (const float*)d_in[3];
    const float* W1  = (const float*)d_in[4];
    const float* b1  = (const float*)d_in[5];
    const float* W2  = (const float*)d_in[6];
    const float* b2  = (const float*)d_in[7];
    const float* W3  = (const float*)d_in[8];
    const float* b3  = (const float*)d_in[9];
    const float* P1  = (const float*)d_in[10];
    const float* pb1 = (const float*)d_in[11];
    const float* P2  = (const float*)d_in[12];
    const float* pb2 = (const float*)d_in[13];

    const int N = NN, E = NE;
    const int NB = (N + 255) / 256;

    uintptr_t p = (uintptr_t)d_ws;
    auto alloc = [&](size_t bytes) -> void* {
        void* r = (void*)p;
        p += (bytes + 255) & ~(size_t)255;
        return r;
    };
    float* deg    = (float*)alloc((size_t)N * 4);
    float* dinv   = (float*)alloc((size_t)N * 4);
    int*   cnt    = (int*)alloc((size_t)N * 4);
    int*   rowptr = (int*)alloc((size_t)(N + 1) * 4);
    int*   cur    = (int*)alloc((size_t)N * 4);
    int*   bsum   = (int*)alloc(256 * 4);
    int2*  epk    = (int2*)alloc((size_t)E * 8);
    unsigned short* Hbf = (unsigned short*)alloc((size_t)N * 256 * 2);
    float* bufB   = (float*)alloc((size_t)N * 256 * 4);
    float* bufT   = (float*)alloc((size_t)N * 128 * 4);
    unsigned short* wf1h = (unsigned short*)alloc(65536 * 2);
    unsigned short* wf1l = (unsigned short*)alloc(65536 * 2);
    unsigned short* wf2h = (unsigned short*)alloc(65536 * 2);
    unsigned short* wf2l = (unsigned short*)alloc(65536 * 2);
    unsigned short* wf3h = (unsigned short*)alloc(32768 * 2);
    unsigned short* wf3l = (unsigned short*)alloc(32768 * 2);
    unsigned short* p1h  = (unsigned short*)alloc(16384 * 2);
    unsigned short* p1l  = (unsigned short*)alloc(16384 * 2);
    unsigned short* p2h  = (unsigned short*)alloc(16384 * 2);
    unsigned short* p2l  = (unsigned short*)alloc(16384 * 2);

    float* emb = (float*)d_out;
    float* z   = (float*)d_out + (size_t)N * 128;

    dim3 b256(256);
    dim3 gN(NB);
    dim3 gE((E + 255) / 256);

    k_wsplit<<<dim3(256), b256, 0, stream>>>(W1, wf1h, wf1l, 256, 256);
    k_wsplit<<<dim3(256), b256, 0, stream>>>(W2, wf2h, wf2l, 256, 256);
    k_wsplit<<<dim3(128), b256, 0, stream>>>(W3, wf3h, wf3l, 256, 128);
    k_wsplit<<<dim3(64),  b256, 0, stream>>>(P1, p1h, p1l, 128, 128);
    k_wsplit<<<dim3(64),  b256, 0, stream>>>(P2, p2h, p2l, 128, 128);

    hipMemsetAsync(cnt, 0, (size_t)N * 4, stream);
    k_init_deg<<<gN, b256, 0, stream>>>(deg, N);
    k_edge_pass1<<<gE, b256, 0, stream>>>(edge_col, edge_val, deg, cnt, E);
    k_dinv<<<gN, b256, 0, stream>>>(deg, dinv, N);
    k_scan_blk<<<gN, b256, 0, stream>>>(cnt, cnt, bsum, N);
    k_scan_top<<<dim3(1), b256, 0, stream>>>(bsum, NB);
    k_scan_add<<<gN, b256, 0, stream>>>(cnt, bsum, rowptr, cur, N, E);
    k_scatter<<<gE, b256, 0, stream>>>(edge_row, edge_col, edge_val, dinv, cur, epk, E);

    const int gm64  = (N + 63) / 64;    // 782
    const int gm128 = (N + 127) / 128;  // 391
    const int gagg  = (N + 3) / 4;      // 12500 blocks, 4 rows each

    // layer 1
    k_mm<64, 256, false, true><<<dim3(gm64, 1), dim3(256), 0, stream>>>(x, wf1h, wf1l, nullptr, Hbf, N, 256, 256);
    k_agg<256, true><<<dim3(gagg), b256, 0, stream>>>(Hbf, rowptr, epk, dinv, b1, bufB);
    // layer 2
    k_mm<64, 256, false, true><<<dim3(gm64, 1), dim3(256), 0, stream>>>(bufB, wf2h, wf2l, nullptr, Hbf, N, 256, 256);
    k_agg<256, true><<<dim3(gagg), b256, 0, stream>>>(Hbf, rowptr, epk, dinv, b2, bufB);
    // layer 3
    k_mm<128, 128, false, true><<<dim3(gm128, 1), dim3(256), 0, stream>>>(bufB, wf3h, wf3l, nullptr, Hbf, N, 256, 128);
    k_agg<128, false><<<dim3(gagg), b256, 0, stream>>>(Hbf, rowptr, epk, dinv, b3, emb);
    // head
    k_mm<64, 128, true,  false><<<dim3(gm64, 1), dim3(128), 0, stream>>>(emb, p1h, p1l, pb1, bufT, N, 128, 128);
    k_mm<64, 128, false, false><<<dim3(gm64, 1), dim3(128), 0, stream>>>(bufT, p2h, p2l, pb2, z, N, 128, 128);
}

// Round 5
// 469.923 us; speedup vs baseline: 1.5688x; 1.0580x over previous
//
#include <hip/hip_runtime.h>
#include <hip/hip_bf16.h>
#include <cstdint>
#include <cstddef>

#define NN 50000
#define NE 800000
#define NRBP 3128  // padded row-chunk count: ceil(50000/16)=3125 -> pad to mult of 8

typedef __attribute__((ext_vector_type(8))) short bf16x8;
typedef __attribute__((ext_vector_type(4))) float f32x4;

static __device__ __forceinline__ unsigned short f2bf_u(float f) {
    __hip_bfloat16 h = __float2bfloat16(f);
    return *reinterpret_cast<unsigned short*>(&h);
}
static __device__ __forceinline__ float bfu2f(unsigned short u) {
    __hip_bfloat16 h = *reinterpret_cast<__hip_bfloat16*>(&u);
    return __bfloat162float(h);
}

// async global->LDS, 16B per lane. lds dst must be wave-uniform (HW adds lane*16).
static __device__ __forceinline__ void gll16(void* lds_dst, const void* gsrc) {
    __builtin_amdgcn_global_load_lds(
        (const __attribute__((address_space(1))) void*)gsrc,
        (__attribute__((address_space(3))) void*)lds_dst, 16, 0, 0);
}

// ---------------- CSR build ----------------

__global__ void k_count(const int* __restrict__ ecol, int* __restrict__ cnt, int e) {
    int i = blockIdx.x * blockDim.x + threadIdx.x;
    if (i < e) atomicAdd(&cnt[ecol[i]], 1);
}

__global__ void k_scan_blk(const int* __restrict__ cnt, int* __restrict__ ex,
                           int* __restrict__ bsum, int n) {
    int tid = threadIdx.x;
    int i = blockIdx.x * 256 + tid;
    int v = (i < n) ? cnt[i] : 0;
    int lane = tid & 63, w = tid >> 6;
    int incl = v;
#pragma unroll
    for (int d = 1; d < 64; d <<= 1) {
        int t = __shfl_up(incl, d);
        if (lane >= d) incl += t;
    }
    __shared__ int wsum[4];
    if (lane == 63) wsum[w] = incl;
    __syncthreads();
    int woff = 0;
    for (int j = 0; j < w; ++j) woff += wsum[j];
    if (i < n) ex[i] = woff + incl - v;
    if (tid == 255) bsum[blockIdx.x] = woff + incl;
}

__global__ void k_scan_top(int* __restrict__ bsum, int nb) {
    int tid = threadIdx.x;
    int v = (tid < nb) ? bsum[tid] : 0;
    int lane = tid & 63, w = tid >> 6;
    int incl = v;
#pragma unroll
    for (int d = 1; d < 64; d <<= 1) {
        int t = __shfl_up(incl, d);
        if (lane >= d) incl += t;
    }
    __shared__ int wsum[4];
    if (lane == 63) wsum[w] = incl;
    __syncthreads();
    int woff = 0;
    for (int j = 0; j < w; ++j) woff += wsum[j];
    if (tid < nb) bsum[tid] = woff + incl - v;
}

__global__ void k_scan_add(const int* __restrict__ ex, const int* __restrict__ boff,
                           int* __restrict__ rowptr, int* __restrict__ cur, int n, int total) {
    int i = blockIdx.x * 256 + threadIdx.x;
    if (i < n) {
        int v = ex[i] + boff[blockIdx.x];
        rowptr[i] = v;
        cur[i] = v;
    }
    if (i == 0) rowptr[n] = total;
}

// scatter edges (src, RAW val) into CSR by destination
__global__ void k_scatter(const int* __restrict__ erow, const int* __restrict__ ecol,
                          const float* __restrict__ eval_,
                          int* __restrict__ cur, int2* __restrict__ epk, int e) {
    int i = blockIdx.x * blockDim.x + threadIdx.x;
    if (i < e) {
        int d = ecol[i];
        int pos = atomicAdd(&cur[d], 1);
        epk[pos] = make_int2(erow[i], __float_as_int(eval_[i]));
    }
}

// deg[i] = 1 + sum(raw val over CSR row i); dinv = rsqrt. Wave per row.
__global__ __launch_bounds__(256) void k_degdinv(const int* __restrict__ rowptr,
                                                 const int2* __restrict__ epk,
                                                 float* __restrict__ dinv) {
    int lane = threadIdx.x & 63;
    int row = blockIdx.x * 4 + (threadIdx.x >> 6);
    if (row >= NN) return;
    int beg = rowptr[row], end = rowptr[row + 1];
    float s = 0.f;
    for (int c = beg + lane; c < end; c += 64) s += __int_as_float(epk[c].y);
#pragma unroll
    for (int d = 1; d < 64; d <<= 1) s += __shfl_xor(s, d);
    if (lane == 0) dinv[row] = rsqrtf(1.f + s);
}

// epk.y := raw_val * dinv[src]  (dst factor applied in agg)
__global__ void k_normw(int2* __restrict__ epk, const float* __restrict__ dinv, int e) {
    int i = blockIdx.x * 256 + threadIdx.x;
    if (i < e) {
        int2 pk = epk[i];
        epk[i].y = __float_as_int(__int_as_float(pk.y) * dinv[pk.x]);
    }
}

// ---------------- sparse aggregation: wave-per-row, shfl indices ----------------
// out[i,:] = dinv_i * ( dinv_i*H[i,:] + sum_e w'_e * H[src_e,:] ) + bias  (opt relu)
// FRAGOUT: write split hi/lo bf16 in GEMM A-fragment layout instead of fp32.
template<int DIM, bool RELU, bool FRAGOUT>
__global__ __launch_bounds__(256) void k_agg(const unsigned short* __restrict__ H,
                      const int* __restrict__ rowptr, const int2* __restrict__ epk,
                      const float* __restrict__ dinv, const float* __restrict__ bias,
                      float* __restrict__ outf, unsigned short* __restrict__ oh,
                      unsigned short* __restrict__ ol) {
    constexpr int WU = DIM / 128;  // uints per lane
    int lane = threadIdx.x & 63;
    int row = blockIdx.x * 4 + (threadIdx.x >> 6);
    if (row >= NN) return;

    const uint2* H2 = reinterpret_cast<const uint2*>(H);
    const unsigned* H1 = reinterpret_cast<const unsigned*>(H);

    auto loadrow = [&](int r, unsigned* v) {
        if constexpr (WU == 2) {
            uint2 t = H2[(size_t)r * 64 + lane];
            v[0] = t.x; v[1] = t.y;
        } else {
            v[0] = H1[(size_t)r * 64 + lane];
        }
    };

    float di = dinv[row];
    float acc[WU * 2];
    {
        unsigned sv[WU];
        loadrow(row, sv);
#pragma unroll
        for (int w2 = 0; w2 < WU; ++w2) {
            acc[w2 * 2 + 0] = di * __uint_as_float(sv[w2] << 16);
            acc[w2 * 2 + 1] = di * __uint_as_float(sv[w2] & 0xffff0000u);
        }
    }

    auto accum = [&](const unsigned* v, float wt) {
#pragma unroll
        for (int w2 = 0; w2 < WU; ++w2) {
            acc[w2 * 2 + 0] += wt * __uint_as_float(v[w2] << 16);
            acc[w2 * 2 + 1] += wt * __uint_as_float(v[w2] & 0xffff0000u);
        }
    };

    int beg = rowptr[row], end = rowptr[row + 1];
    for (int c = beg; c < end; c += 64) {
        int m = min(64, end - c);
        int2 pk = make_int2(0, 0);
        if (c + lane < end) pk = epk[c + lane];
        int j = 0;
        for (; j + 4 <= m; j += 4) {
            int s0 = __shfl(pk.x, j + 0), s1 = __shfl(pk.x, j + 1);
            int s2 = __shfl(pk.x, j + 2), s3 = __shfl(pk.x, j + 3);
            float w0 = __int_as_float(__shfl(pk.y, j + 0));
            float w1 = __int_as_float(__shfl(pk.y, j + 1));
            float w2 = __int_as_float(__shfl(pk.y, j + 2));
            float w3 = __int_as_float(__shfl(pk.y, j + 3));
            unsigned g0[WU], g1[WU], g2[WU], g3[WU];
            loadrow(s0, g0);
            loadrow(s1, g1);
            loadrow(s2, g2);
            loadrow(s3, g3);
            accum(g0, w0);
            accum(g1, w1);
            accum(g2, w2);
            accum(g3, w3);
        }
        for (; j < m; ++j) {
            int s = __shfl(pk.x, j);
            float wt = __int_as_float(__shfl(pk.y, j));
            unsigned g[WU];
            loadrow(s, g);
            accum(g, wt);
        }
    }

    if constexpr (FRAGOUT) {
        // DIM==256: cols 4*lane..4*lane+3
        float4 b4 = reinterpret_cast<const float4*>(bias)[lane];
        float o0 = acc[0] * di + b4.x;
        float o1 = acc[1] * di + b4.y;
        float o2 = acc[2] * di + b4.z;
        float o3 = acc[3] * di + b4.w;
        if (RELU) {
            o0 = fmaxf(o0, 0.f); o1 = fmaxf(o1, 0.f);
            o2 = fmaxf(o2, 0.f); o3 = fmaxf(o3, 0.f);
        }
        ushort4 h, lo;
        h.x = f2bf_u(o0); lo.x = f2bf_u(o0 - bfu2f(h.x));
        h.y = f2bf_u(o1); lo.y = f2bf_u(o1 - bfu2f(h.y));
        h.z = f2bf_u(o2); lo.z = f2bf_u(o2 - bfu2f(h.z));
        h.w = f2bf_u(o3); lo.w = f2bf_u(o3 - bfu2f(h.w));
        size_t chunk = (size_t)(lane >> 3) * NRBP + (row >> 4);
        int off = ((lane & 7) >> 1) * 128 + (row & 15) * 8 + (lane & 1) * 4;
        *reinterpret_cast<ushort4*>(&oh[chunk * 512 + off]) = h;
        *reinterpret_cast<ushort4*>(&ol[chunk * 512 + off]) = lo;
    } else if constexpr (WU == 2) {
        float4 b4 = reinterpret_cast<const float4*>(bias)[lane];
        float4 o;
        o.x = acc[0] * di + b4.x; o.y = acc[1] * di + b4.y;
        o.z = acc[2] * di + b4.z; o.w = acc[3] * di + b4.w;
        if (RELU) {
            o.x = fmaxf(o.x, 0.f); o.y = fmaxf(o.y, 0.f);
            o.z = fmaxf(o.z, 0.f); o.w = fmaxf(o.w, 0.f);
        }
        reinterpret_cast<float4*>(outf)[(size_t)row * 64 + lane] = o;
    } else {
        float2 b2 = reinterpret_cast<const float2*>(bias)[lane];
        float2 o;
        o.x = acc[0] * di + b2.x; o.y = acc[1] * di + b2.y;
        if (RELU) { o.x = fmaxf(o.x, 0.f); o.y = fmaxf(o.y, 0.f); }
        reinterpret_cast<float2*>(outf)[(size_t)row * 64 + lane] = o;
    }
}

// ---------------- pre-split x (fp32 [N][256]) into frag-layout hi/lo planes -------
__global__ void k_xsplit(const float* __restrict__ X, unsigned short* __restrict__ xh,
                         unsigned short* __restrict__ xl, int nrows) {
    int idx = blockIdx.x * 256 + threadIdx.x;
    int row = idx >> 6, t = idx & 63;
    if (row >= nrows) return;
    float4 v = *reinterpret_cast<const float4*>(&X[(size_t)row * 256 + t * 4]);
    ushort4 h, lo;
    h.x = f2bf_u(v.x); lo.x = f2bf_u(v.x - bfu2f(h.x));
    h.y = f2bf_u(v.y); lo.y = f2bf_u(v.y - bfu2f(h.y));
    h.z = f2bf_u(v.z); lo.z = f2bf_u(v.z - bfu2f(h.z));
    h.w = f2bf_u(v.w); lo.w = f2bf_u(v.w - bfu2f(h.w));
    size_t chunk = (size_t)(t >> 3) * NRBP + (row >> 4);
    int off = ((t & 7) >> 1) * 128 + (row & 15) * 8 + (t & 1) * 4;
    *reinterpret_cast<ushort4*>(&xh[chunk * 512 + off]) = h;
    *reinterpret_cast<ushort4*>(&xl[chunk * 512 + off]) = lo;
}

// ---------------- weight pre-split into frag-ordered hi/lo bf16 ----------------
// layout: [kb=K/32][nb=M/16] chunks of 512 shorts: [kg=4][c=16][kj=8]
__global__ void k_wsplit(const float* __restrict__ W, unsigned short* __restrict__ wh,
                         unsigned short* __restrict__ wl, int K, int M) {
    int idx = blockIdx.x * blockDim.x + threadIdx.x;
    if (idx >= K * M) return;
    int k = idx / M, m = idx % M;
    float w = W[idx];
    unsigned short h = f2bf_u(w);
    float hf = bfu2f(h);
    unsigned short lo = f2bf_u(w - hf);
    int kb = k >> 5, kg = (k & 31) >> 3, kj = k & 7;
    int nb = m >> 4, c = m & 15;
    int off = (kb * (M >> 4) + nb) * 512 + kg * 128 + c * 8 + kj;
    wh[off] = h;
    wl[off] = lo;
}

// ---------------- pipelined MFMA GEMM, frag-layout inputs, bf16 out -------------
// A: hi/lo frag planes [kb][rowchunk(NRBP)][512]; W: [kb][nb][512].
// Double-buffered LDS, async global_load_lds staging, prefetch before compute.
template<int BM, int BN>
__global__ __launch_bounds__((BM / 64) * (BN / 64) * 64)
void k_mmf(const unsigned short* __restrict__ ah, const unsigned short* __restrict__ al,
           const unsigned short* __restrict__ wh, const unsigned short* __restrict__ wl,
           unsigned short* __restrict__ Cbf, int nrows, int K, int M) {
    constexpr int NW = (BM / 64) * (BN / 64);
    constexpr int WN = BN / 64;
    constexpr int AC = BM / 16, BC = BN / 16;
    constexpr int TC = 2 * (AC + BC);
    constexpr int BUF = TC * 512;  // shorts
    __shared__ unsigned short sm[2 * BUF];
    const int tid = threadIdx.x, l = tid & 63, wid = tid >> 6;
    const int wr = wid / WN, wc = wid % WN;
    const int bm = blockIdx.x * BM, bn = blockIdx.y * BN;
    const int rb0 = blockIdx.x * AC, nb0 = blockIdx.y * BC;
    const int NKB = K >> 5, MB = M >> 4;
    const int fo = (l >> 4) * 128 + (l & 15) * 8;
    f32x4 acc[4][4] = {};

    auto stage = [&](int buf, int kb) {
        unsigned short* base = sm + buf * BUF;
        const unsigned short* ga_h = ah + ((size_t)kb * NRBP + rb0) * 512;
        const unsigned short* ga_l = al + ((size_t)kb * NRBP + rb0) * 512;
        const unsigned short* gb_h = wh + ((size_t)kb * MB + nb0) * 512;
        const unsigned short* gb_l = wl + ((size_t)kb * MB + nb0) * 512;
        for (int q = wid; q < TC; q += NW) {
            const unsigned short* s;
            if (q < AC) s = ga_h + q * 512;
            else if (q < 2 * AC) s = ga_l + (q - AC) * 512;
            else if (q < 2 * AC + BC) s = gb_h + (q - 2 * AC) * 512;
            else s = gb_l + (q - 2 * AC - BC) * 512;
            gll16(base + q * 512, s + l * 8);
        }
    };

    stage(0, 0);
    __syncthreads();  // drains vmcnt before first reads
    for (int kb = 0; kb < NKB; ++kb) {
        const int cur = kb & 1;
        if (kb + 1 < NKB) stage(cur ^ 1, kb + 1);  // prefetch flies over compute
        const unsigned short* base = sm + cur * BUF;
        bf16x8 a_h[4], a_l[4], b_h[4], b_l[4];
#pragma unroll
        for (int i = 0; i < 4; ++i) {
            a_h[i] = *reinterpret_cast<const bf16x8*>(base + (wr * 4 + i) * 512 + fo);
            a_l[i] = *reinterpret_cast<const bf16x8*>(base + (AC + wr * 4 + i) * 512 + fo);
        }
#pragma unroll
        for (int j = 0; j < 4; ++j) {
            b_h[j] = *reinterpret_cast<const bf16x8*>(base + (2 * AC + wc * 4 + j) * 512 + fo);
            b_l[j] = *reinterpret_cast<const bf16x8*>(base + (2 * AC + BC + wc * 4 + j) * 512 + fo);
        }
#pragma unroll
        for (int i = 0; i < 4; ++i)
#pragma unroll
            for (int j = 0; j < 4; ++j) {
                acc[i][j] = __builtin_amdgcn_mfma_f32_16x16x32_bf16(a_h[i], b_h[j], acc[i][j], 0, 0, 0);
                acc[i][j] = __builtin_amdgcn_mfma_f32_16x16x32_bf16(a_h[i], b_l[j], acc[i][j], 0, 0, 0);
                acc[i][j] = __builtin_amdgcn_mfma_f32_16x16x32_bf16(a_l[i], b_h[j], acc[i][j], 0, 0, 0);
            }
        __syncthreads();  // also drains prefetch vmcnt -> next buf ready
    }
#pragma unroll
    for (int j = 0; j < 4; ++j) {
        int col = bn + wc * 64 + j * 16 + (l & 15);
#pragma unroll
        for (int i = 0; i < 4; ++i) {
            int row0 = bm + wr * 64 + i * 16 + (l >> 4) * 4;
#pragma unroll
            for (int r = 0; r < 4; ++r) {
                int row = row0 + r;
                if (row < nrows)
                    Cbf[(size_t)row * M + col] = f2bf_u(acc[i][j][r]);
            }
        }
    }
}

// ---------------- head GEMM (fp32 A, in-kernel split, 3-pass) -------------------
template<int BM, int BN, bool RELU>
__global__ __launch_bounds__((BM / 64) * (BN / 64) * 64)
void k_mm(const float* __restrict__ A, const unsigned short* __restrict__ wh,
          const unsigned short* __restrict__ wl, const float* __restrict__ bias,
          float* __restrict__ Cout, int nrows, int K, int M) {
    constexpr int T = (BM / 64) * (BN / 64) * 64;
    constexpr int WN = BN / 64;
    constexpr int QI = BM * 8 / T;
    __shared__ unsigned short Ah[BM * 32], Al[BM * 32], Bh[BN * 32], Bl[BN * 32];
    int tid = threadIdx.x;
    int l = tid & 63;
    int wid = tid >> 6;
    int wr = wid / WN, wc = wid % WN;
    int bm = blockIdx.x * BM, bn = blockIdx.y * BN;
    int nb0 = bn >> 4;
    f32x4 acc[4][4] = {};
    int fo = (l >> 4) * 128 + (l & 15) * 8;

    for (int k0 = 0; k0 < K; k0 += 32) {
        int kb = k0 >> 5;
#pragma unroll
        for (int q = 0; q < QI; ++q) {
            int t2 = tid + q * T;
            int row = t2 >> 3, kq = t2 & 7;
            int grow = bm + row;
            float4 av = make_float4(0.f, 0.f, 0.f, 0.f);
            if (grow < nrows)
                av = *reinterpret_cast<const float4*>(&A[(size_t)grow * K + k0 + kq * 4]);
            unsigned short h0 = f2bf_u(av.x), h1 = f2bf_u(av.y),
                           h2 = f2bf_u(av.z), h3 = f2bf_u(av.w);
            uint2 hp, lp;
            hp.x = (unsigned)h0 | ((unsigned)h1 << 16);
            hp.y = (unsigned)h2 | ((unsigned)h3 << 16);
            lp.x = (unsigned)f2bf_u(av.x - bfu2f(h0)) | ((unsigned)f2bf_u(av.y - bfu2f(h1)) << 16);
            lp.y = (unsigned)f2bf_u(av.z - bfu2f(h2)) | ((unsigned)f2bf_u(av.w - bfu2f(h3)) << 16);
            int off = (row >> 4) * 512 + (kq >> 1) * 128 + (row & 15) * 8 + (kq & 1) * 4;
            *reinterpret_cast<uint2*>(&Ah[off]) = hp;
            *reinterpret_cast<uint2*>(&Al[off]) = lp;
        }
        const int4* sh = reinterpret_cast<const int4*>(wh) + (size_t)(kb * (M >> 4) + nb0) * 64;
        const int4* sl = reinterpret_cast<const int4*>(wl) + (size_t)(kb * (M >> 4) + nb0) * 64;
        for (int u = tid; u < BN * 4; u += T) {
            *reinterpret_cast<int4*>(&Bh[u * 8]) = sh[u];
            *reinterpret_cast<int4*>(&Bl[u * 8]) = sl[u];
        }
        __syncthreads();
        bf16x8 ah4[4], al4[4], bh4[4], bl4[4];
#pragma unroll
        for (int i = 0; i < 4; ++i) {
            ah4[i] = *reinterpret_cast<const bf16x8*>(&Ah[(wr * 4 + i) * 512 + fo]);
            al4[i] = *reinterpret_cast<const bf16x8*>(&Al[(wr * 4 + i) * 512 + fo]);
        }
#pragma unroll
        for (int j = 0; j < 4; ++j) {
            bh4[j] = *reinterpret_cast<const bf16x8*>(&Bh[(wc * 4 + j) * 512 + fo]);
            bl4[j] = *reinterpret_cast<const bf16x8*>(&Bl[(wc * 4 + j) * 512 + fo]);
        }
#pragma unroll
        for (int i = 0; i < 4; ++i)
#pragma unroll
            for (int j = 0; j < 4; ++j) {
                acc[i][j] = __builtin_amdgcn_mfma_f32_16x16x32_bf16(ah4[i], bh4[j], acc[i][j], 0, 0, 0);
                acc[i][j] = __builtin_amdgcn_mfma_f32_16x16x32_bf16(ah4[i], bl4[j], acc[i][j], 0, 0, 0);
                acc[i][j] = __builtin_amdgcn_mfma_f32_16x16x32_bf16(al4[i], bh4[j], acc[i][j], 0, 0, 0);
            }
        __syncthreads();
    }
#pragma unroll
    for (int j = 0; j < 4; ++j) {
        int col = bn + wc * 64 + j * 16 + (l & 15);
        float bv = bias[col];
#pragma unroll
        for (int i = 0; i < 4; ++i) {
            int row0 = bm + wr * 64 + i * 16 + (l >> 4) * 4;
#pragma unroll
            for (int r = 0; r < 4; ++r) {
                int row = row0 + r;
                if (row < nrows) {
                    float v = acc[i][j][r] + bv;
                    if (RELU) v = fmaxf(v, 0.f);
                    Cout[(size_t)row * M + col] = v;
                }
            }
        }
    }
}

// ---------------- launch ----------------

extern "C" void kernel_launch(void* const* d_in, const int* in_sizes, int n_in,
                              void* d_out, int out_size, void* d_ws, size_t ws_size,
                              hipStream_t stream) {
    const float* x        = (const float*)d_in[0];
    const int*   edge_row = (const int*)d_in[1];
    const int*   edge_col = (const int*)d_in[2];
    const float* edge_val = (const float*)d_in[3];
    const float* W1  = (const float*)d_in[4];
    const float* b1  = (const float*)d_in[5];
    const float* W2  = (const float*)d_in[6];
    const float* b2  = (const float*)d_in[7];
    const float* W3  = (const float*)d_in[8];
    const float* b3  = (const float*)d_in[9];
    const float* P1  = (const float*)d_in[10];
    const float* pb1 = (const float*)d_in[11];
    const float* P2  = (const float*)d_in[12];
    const float* pb2 = (const float*)d_in[13];

    const int N = NN, E = NE;
    const int NB = (N + 255) / 256;  // 196

    uintptr_t p = (uintptr_t)d_ws;
    auto alloc = [&](size_t bytes) -> void* {
        void* r = (void*)p;
        p += (bytes + 255) & ~(size_t)255;
        return r;
    };
    float* dinv   = (float*)alloc((size_t)N * 4);
    int*   cnt    = (int*)alloc((size_t)N * 4);
    int*   rowptr = (int*)alloc((size_t)(N + 1) * 4);
    int*   cur    = (int*)alloc((size_t)N * 4);
    int*   bsum   = (int*)alloc(256 * 4);
    int2*  epk    = (int2*)alloc((size_t)E * 8);
    unsigned short* Hbf = (unsigned short*)alloc((size_t)N * 256 * 2);
    // frag planes: 8 kb-chunks x NRBP rowchunks x 1KB
    const size_t PLANE = (size_t)8 * NRBP * 512 * 2;  // bytes
    unsigned short* pAh = (unsigned short*)alloc(PLANE);
    unsigned short* pAl = (unsigned short*)alloc(PLANE);
    unsigned short* pBh = (unsigned short*)alloc(PLANE);
    unsigned short* pBl = (unsigned short*)alloc(PLANE);
    float* bufT = (float*)pBh;  // head intermediate aliases pBh (free after GEMM3)
    unsigned short* wf1h = (unsigned short*)alloc(65536 * 2);
    unsigned short* wf1l = (unsigned short*)alloc(65536 * 2);
    unsigned short* wf2h = (unsigned short*)alloc(65536 * 2);
    unsigned short* wf2l = (unsigned short*)alloc(65536 * 2);
    unsigned short* wf3h = (unsigned short*)alloc(32768 * 2);
    unsigned short* wf3l = (unsigned short*)alloc(32768 * 2);
    unsigned short* p1h  = (unsigned short*)alloc(16384 * 2);
    unsigned short* p1l  = (unsigned short*)alloc(16384 * 2);
    unsigned short* p2h  = (unsigned short*)alloc(16384 * 2);
    unsigned short* p2l  = (unsigned short*)alloc(16384 * 2);

    float* emb = (float*)d_out;
    float* z   = (float*)d_out + (size_t)N * 128;

    dim3 b256(256);
    dim3 gE((E + 255) / 256);

    // weight splits + x split
    k_wsplit<<<dim3(256), b256, 0, stream>>>(W1, wf1h, wf1l, 256, 256);
    k_wsplit<<<dim3(256), b256, 0, stream>>>(W2, wf2h, wf2l, 256, 256);
    k_wsplit<<<dim3(128), b256, 0, stream>>>(W3, wf3h, wf3l, 256, 128);
    k_wsplit<<<dim3(64),  b256, 0, stream>>>(P1, p1h, p1l, 128, 128);
    k_wsplit<<<dim3(64),  b256, 0, stream>>>(P2, p2h, p2l, 128, 128);
    k_xsplit<<<dim3((N * 64 + 255) / 256), b256, 0, stream>>>(x, pAh, pAl, N);

    // CSR build (count -> scan -> scatter raw -> deg/dinv -> normalize weights)
    hipMemsetAsync(cnt, 0, (size_t)N * 4, stream);
    k_count<<<gE, b256, 0, stream>>>(edge_col, cnt, E);
    k_scan_blk<<<dim3(NB), b256, 0, stream>>>(cnt, cnt, bsum, N);
    k_scan_top<<<dim3(1), b256, 0, stream>>>(bsum, NB);
    k_scan_add<<<dim3(NB), b256, 0, stream>>>(cnt, bsum, rowptr, cur, N, E);
    k_scatter<<<gE, b256, 0, stream>>>(edge_row, edge_col, edge_val, cur, epk, E);
    k_degdinv<<<dim3((N + 3) / 4), b256, 0, stream>>>(rowptr, epk, dinv);
    k_normw<<<gE, b256, 0, stream>>>(epk, dinv, E);

    const int gagg = (N + 3) / 4;  // 12500

    // layer 1: Hbf = x @ W1 ; pB = split(relu(agg(Hbf)*dinv + b1))
    k_mmf<128, 128><<<dim3(391, 2), dim3(256), 0, stream>>>(pAh, pAl, wf1h, wf1l, Hbf, N, 256, 256);
    k_agg<256, true, true><<<dim3(gagg), b256, 0, stream>>>(Hbf, rowptr, epk, dinv, b1, nullptr, pBh, pBl);
    // layer 2
    k_mmf<128, 128><<<dim3(391, 2), dim3(256), 0, stream>>>(pBh, pBl, wf2h, wf2l, Hbf, N, 256, 256);
    k_agg<256, true, true><<<dim3(gagg), b256, 0, stream>>>(Hbf, rowptr, epk, dinv, b2, nullptr, pAh, pAl);
    // layer 3
    k_mmf<64, 128><<<dim3(782, 1), dim3(128), 0, stream>>>(pAh, pAl, wf3h, wf3l, Hbf, N, 256, 128);
    k_agg<128, false, false><<<dim3(gagg), b256, 0, stream>>>(Hbf, rowptr, epk, dinv, b3, emb, nullptr, nullptr);
    // head: z = relu(emb @ P1 + pb1) @ P2 + pb2
    k_mm<64, 128, true ><<<dim3(782, 1), dim3(128), 0, stream>>>(emb, p1h, p1l, pb1, bufT, N, 128, 128);
    k_mm<64, 128, false><<<dim3(782, 1), dim3(128), 0, stream>>>(bufT, p2h, p2l, pb2, z, N, 128, 128);
}

// Round 6
// 430.002 us; speedup vs baseline: 1.7145x; 1.0928x over previous
//
#include <hip/hip_runtime.h>
#include <hip/hip_bf16.h>
#include <cstdint>
#include <cstddef>

#define NN 50000
#define NE 800000
#define NRBP 3128  // padded row-chunk count: ceil(50000/16)=3125 -> pad to mult of 8
#define NBK 196    // coarse buckets: dest >> 8  (50000/256 -> 196)

typedef __attribute__((ext_vector_type(8))) short bf16x8;
typedef __attribute__((ext_vector_type(4))) float f32x4;

static __device__ __forceinline__ unsigned short f2bf_u(float f) {
    __hip_bfloat16 h = __float2bfloat16(f);
    return *reinterpret_cast<unsigned short*>(&h);
}
static __device__ __forceinline__ float bfu2f(unsigned short u) {
    __hip_bfloat16 h = *reinterpret_cast<__hip_bfloat16*>(&u);
    return __bfloat162float(h);
}

// async global->LDS, 16B per lane. lds dst must be wave-uniform (HW adds lane*16).
static __device__ __forceinline__ void gll16(void* lds_dst, const void* gsrc) {
    __builtin_amdgcn_global_load_lds(
        (const __attribute__((address_space(1))) void*)gsrc,
        (__attribute__((address_space(3))) void*)lds_dst, 16, 0, 0);
}

// ================= CSR build: bucket sort (LDS-localized, low atomic thrash) ====

// p1: coarse bucket histogram. 1024 edges/block, LDS bins, 1 global atomic/bin/block.
__global__ __launch_bounds__(256) void k_bhist(const int* __restrict__ ecol,
                                               int* __restrict__ bcnt, int e) {
    __shared__ int lcnt[NBK];
    int tid = threadIdx.x;
    for (int t = tid; t < NBK; t += 256) lcnt[t] = 0;
    __syncthreads();
#pragma unroll
    for (int q = 0; q < 4; ++q) {
        int i = blockIdx.x * 1024 + q * 256 + tid;
        if (i < e) atomicAdd(&lcnt[ecol[i] >> 8], 1);
    }
    __syncthreads();
    for (int t = tid; t < NBK; t += 256)
        if (lcnt[t]) atomicAdd(&bcnt[t], lcnt[t]);
}

// p2: exclusive scan of 196 bucket counts -> boff (197 entries), gcur copy, rowptr[NN].
__global__ void k_bscan(const int* __restrict__ bcnt, int* __restrict__ boff,
                        int* __restrict__ gcur, int* __restrict__ rowptr) {
    int tid = threadIdx.x;
    int v = (tid < NBK) ? bcnt[tid] : 0;
    int lane = tid & 63, w = tid >> 6;
    int incl = v;
#pragma unroll
    for (int d = 1; d < 64; d <<= 1) {
        int t = __shfl_up(incl, d);
        if (lane >= d) incl += t;
    }
    __shared__ int wsum[4];
    if (lane == 63) wsum[w] = incl;
    __syncthreads();
    int woff = 0;
    for (int j = 0; j < w; ++j) woff += wsum[j];
    int ex = woff + incl - v;
    if (tid < NBK) { boff[tid] = ex; gcur[tid] = ex; }
    if (tid == 255) { boff[NBK] = ex; rowptr[NN] = ex; }  // ex == total == E here
}

// p3: scatter edges into bucket-grouped order. Packed: x = src | (dlow<<20), y = raw val.
__global__ __launch_bounds__(256) void k_bscat(const int* __restrict__ erow,
                                               const int* __restrict__ ecol,
                                               const float* __restrict__ eval_,
                                               int* __restrict__ gcur,
                                               int2* __restrict__ tmp, int e) {
    __shared__ int lcnt[NBK], lbase[NBK], lcur[NBK];
    int tid = threadIdx.x;
    for (int t = tid; t < NBK; t += 256) { lcnt[t] = 0; lcur[t] = 0; }
    __syncthreads();
    int d_[4], b_[4];
#pragma unroll
    for (int q = 0; q < 4; ++q) {
        int i = blockIdx.x * 1024 + q * 256 + tid;
        d_[q] = -1;
        if (i < e) {
            d_[q] = ecol[i];
            b_[q] = d_[q] >> 8;
            atomicAdd(&lcnt[b_[q]], 1);
        }
    }
    __syncthreads();
    for (int t = tid; t < NBK; t += 256)
        lbase[t] = lcnt[t] ? atomicAdd(&gcur[t], lcnt[t]) : 0;
    __syncthreads();
#pragma unroll
    for (int q = 0; q < 4; ++q) {
        int i = blockIdx.x * 1024 + q * 256 + tid;
        if (i < e) {
            int b = b_[q];
            int pos = lbase[b] + atomicAdd(&lcur[b], 1);
            tmp[pos] = make_int2(erow[i] | ((d_[q] & 255) << 20), __float_as_int(eval_[i]));
        }
    }
}

// p4: block per bucket. LDS histogram over 256 in-bucket dests -> rowptr, deg/dinv,
// then scatter to final CSR position (writes confined to bucket's ~32KB window).
__global__ __launch_bounds__(256) void k_bsort(const int2* __restrict__ tmp,
                                               const int* __restrict__ boff,
                                               int* __restrict__ rowptr,
                                               float* __restrict__ dinv,
                                               int2* __restrict__ epk) {
    __shared__ int lcnt[256], lcur[256];
    __shared__ float ldeg[256];
    __shared__ int wsum[4];
    int tid = threadIdx.x;
    int b = blockIdx.x;
    int base = boff[b], endb = boff[b + 1];
    lcnt[tid] = 0;
    ldeg[tid] = 0.f;
    __syncthreads();
    for (int i = base + tid; i < endb; i += 256) {
        int2 e2 = tmp[i];
        int d = e2.x >> 20;
        atomicAdd(&lcnt[d], 1);
        atomicAdd(&ldeg[d], __int_as_float(e2.y));
    }
    __syncthreads();
    // exclusive scan of lcnt[256]
    int v = lcnt[tid];
    int lane = tid & 63, w = tid >> 6;
    int incl = v;
#pragma unroll
    for (int d = 1; d < 64; d <<= 1) {
        int t = __shfl_up(incl, d);
        if (lane >= d) incl += t;
    }
    if (lane == 63) wsum[w] = incl;
    __syncthreads();
    int woff = 0;
    for (int j = 0; j < w; ++j) woff += wsum[j];
    int ex = woff + incl - v;
    int dest = (b << 8) + tid;
    if (dest < NN) {
        rowptr[dest] = base + ex;
        dinv[dest] = rsqrtf(1.f + ldeg[tid]);
    }
    lcur[tid] = ex;
    __syncthreads();
    for (int i = base + tid; i < endb; i += 256) {
        int2 e2 = tmp[i];
        int d = e2.x >> 20;
        int pos = base + atomicAdd(&lcur[d], 1);
        epk[pos] = make_int2(e2.x & 0xFFFFF, e2.y);
    }
}

// epk.y := raw_val * dinv[src]  (dst factor applied in agg)
__global__ void k_normw(int2* __restrict__ epk, const float* __restrict__ dinv, int e) {
    int i = blockIdx.x * 256 + threadIdx.x;
    if (i < e) {
        int2 pk = epk[i];
        epk[i].y = __float_as_int(__int_as_float(pk.y) * dinv[pk.x]);
    }
}

// ---------------- sparse aggregation: wave-per-row, shfl indices ----------------
// out[i,:] = dinv_i * ( dinv_i*H[i,:] + sum_e w'_e * H[src_e,:] ) + bias  (opt relu)
// FRAGOUT: write split hi/lo bf16 in GEMM A-fragment layout instead of fp32.
template<int DIM, bool RELU, bool FRAGOUT>
__global__ __launch_bounds__(256) void k_agg(const unsigned short* __restrict__ H,
                      const int* __restrict__ rowptr, const int2* __restrict__ epk,
                      const float* __restrict__ dinv, const float* __restrict__ bias,
                      float* __restrict__ outf, unsigned short* __restrict__ oh,
                      unsigned short* __restrict__ ol) {
    constexpr int WU = DIM / 128;  // uints per lane
    int lane = threadIdx.x & 63;
    int row = blockIdx.x * 4 + (threadIdx.x >> 6);
    if (row >= NN) return;

    const uint2* H2 = reinterpret_cast<const uint2*>(H);
    const unsigned* H1 = reinterpret_cast<const unsigned*>(H);

    auto loadrow = [&](int r, unsigned* v) {
        if constexpr (WU == 2) {
            uint2 t = H2[(size_t)r * 64 + lane];
            v[0] = t.x; v[1] = t.y;
        } else {
            v[0] = H1[(size_t)r * 64 + lane];
        }
    };

    float di = dinv[row];
    float acc[WU * 2];
    {
        unsigned sv[WU];
        loadrow(row, sv);
#pragma unroll
        for (int w2 = 0; w2 < WU; ++w2) {
            acc[w2 * 2 + 0] = di * __uint_as_float(sv[w2] << 16);
            acc[w2 * 2 + 1] = di * __uint_as_float(sv[w2] & 0xffff0000u);
        }
    }

    auto accum = [&](const unsigned* v, float wt) {
#pragma unroll
        for (int w2 = 0; w2 < WU; ++w2) {
            acc[w2 * 2 + 0] += wt * __uint_as_float(v[w2] << 16);
            acc[w2 * 2 + 1] += wt * __uint_as_float(v[w2] & 0xffff0000u);
        }
    };

    int beg = rowptr[row], end = rowptr[row + 1];
    for (int c = beg; c < end; c += 64) {
        int m = min(64, end - c);
        int2 pk = make_int2(0, 0);
        if (c + lane < end) pk = epk[c + lane];
        int j = 0;
        for (; j + 4 <= m; j += 4) {
            int s0 = __shfl(pk.x, j + 0), s1 = __shfl(pk.x, j + 1);
            int s2 = __shfl(pk.x, j + 2), s3 = __shfl(pk.x, j + 3);
            float w0 = __int_as_float(__shfl(pk.y, j + 0));
            float w1 = __int_as_float(__shfl(pk.y, j + 1));
            float w2 = __int_as_float(__shfl(pk.y, j + 2));
            float w3 = __int_as_float(__shfl(pk.y, j + 3));
            unsigned g0[WU], g1[WU], g2[WU], g3[WU];
            loadrow(s0, g0);
            loadrow(s1, g1);
            loadrow(s2, g2);
            loadrow(s3, g3);
            accum(g0, w0);
            accum(g1, w1);
            accum(g2, w2);
            accum(g3, w3);
        }
        for (; j < m; ++j) {
            int s = __shfl(pk.x, j);
            float wt = __int_as_float(__shfl(pk.y, j));
            unsigned g[WU];
            loadrow(s, g);
            accum(g, wt);
        }
    }

    if constexpr (FRAGOUT) {
        // DIM==256: cols 4*lane..4*lane+3
        float4 b4 = reinterpret_cast<const float4*>(bias)[lane];
        float o0 = acc[0] * di + b4.x;
        float o1 = acc[1] * di + b4.y;
        float o2 = acc[2] * di + b4.z;
        float o3 = acc[3] * di + b4.w;
        if (RELU) {
            o0 = fmaxf(o0, 0.f); o1 = fmaxf(o1, 0.f);
            o2 = fmaxf(o2, 0.f); o3 = fmaxf(o3, 0.f);
        }
        ushort4 h, lo;
        h.x = f2bf_u(o0); lo.x = f2bf_u(o0 - bfu2f(h.x));
        h.y = f2bf_u(o1); lo.y = f2bf_u(o1 - bfu2f(h.y));
        h.z = f2bf_u(o2); lo.z = f2bf_u(o2 - bfu2f(h.z));
        h.w = f2bf_u(o3); lo.w = f2bf_u(o3 - bfu2f(h.w));
        size_t chunk = (size_t)(lane >> 3) * NRBP + (row >> 4);
        int off = ((lane & 7) >> 1) * 128 + (row & 15) * 8 + (lane & 1) * 4;
        *reinterpret_cast<ushort4*>(&oh[chunk * 512 + off]) = h;
        *reinterpret_cast<ushort4*>(&ol[chunk * 512 + off]) = lo;
    } else if constexpr (WU == 2) {
        float4 b4 = reinterpret_cast<const float4*>(bias)[lane];
        float4 o;
        o.x = acc[0] * di + b4.x; o.y = acc[1] * di + b4.y;
        o.z = acc[2] * di + b4.z; o.w = acc[3] * di + b4.w;
        if (RELU) {
            o.x = fmaxf(o.x, 0.f); o.y = fmaxf(o.y, 0.f);
            o.z = fmaxf(o.z, 0.f); o.w = fmaxf(o.w, 0.f);
        }
        reinterpret_cast<float4*>(outf)[(size_t)row * 64 + lane] = o;
    } else {
        float2 b2 = reinterpret_cast<const float2*>(bias)[lane];
        float2 o;
        o.x = acc[0] * di + b2.x; o.y = acc[1] * di + b2.y;
        if (RELU) { o.x = fmaxf(o.x, 0.f); o.y = fmaxf(o.y, 0.f); }
        reinterpret_cast<float2*>(outf)[(size_t)row * 64 + lane] = o;
    }
}

// ---------------- pre-split x (fp32 [N][256]) into frag-layout hi/lo planes -------
__global__ void k_xsplit(const float* __restrict__ X, unsigned short* __restrict__ xh,
                         unsigned short* __restrict__ xl, int nrows) {
    int idx = blockIdx.x * 256 + threadIdx.x;
    int row = idx >> 6, t = idx & 63;
    if (row >= nrows) return;
    float4 v = *reinterpret_cast<const float4*>(&X[(size_t)row * 256 + t * 4]);
    ushort4 h, lo;
    h.x = f2bf_u(v.x); lo.x = f2bf_u(v.x - bfu2f(h.x));
    h.y = f2bf_u(v.y); lo.y = f2bf_u(v.y - bfu2f(h.y));
    h.z = f2bf_u(v.z); lo.z = f2bf_u(v.z - bfu2f(h.z));
    h.w = f2bf_u(v.w); lo.w = f2bf_u(v.w - bfu2f(h.w));
    size_t chunk = (size_t)(t >> 3) * NRBP + (row >> 4);
    int off = ((t & 7) >> 1) * 128 + (row & 15) * 8 + (t & 1) * 4;
    *reinterpret_cast<ushort4*>(&xh[chunk * 512 + off]) = h;
    *reinterpret_cast<ushort4*>(&xl[chunk * 512 + off]) = lo;
}

// ---------------- weight pre-split into frag-ordered hi/lo bf16 ----------------
// layout: [kb=K/32][nb=M/16] chunks of 512 shorts: [kg=4][c=16][kj=8]
__global__ void k_wsplit(const float* __restrict__ W, unsigned short* __restrict__ wh,
                         unsigned short* __restrict__ wl, int K, int M) {
    int idx = blockIdx.x * blockDim.x + threadIdx.x;
    if (idx >= K * M) return;
    int k = idx / M, m = idx % M;
    float w = W[idx];
    unsigned short h = f2bf_u(w);
    float hf = bfu2f(h);
    unsigned short lo = f2bf_u(w - hf);
    int kb = k >> 5, kg = (k & 31) >> 3, kj = k & 7;
    int nb = m >> 4, c = m & 15;
    int off = (kb * (M >> 4) + nb) * 512 + kg * 128 + c * 8 + kj;
    wh[off] = h;
    wl[off] = lo;
}

// ---------------- pipelined MFMA GEMM, frag-layout inputs, bf16 out -------------
template<int BM, int BN>
__global__ __launch_bounds__((BM / 64) * (BN / 64) * 64)
void k_mmf(const unsigned short* __restrict__ ah, const unsigned short* __restrict__ al,
           const unsigned short* __restrict__ wh, const unsigned short* __restrict__ wl,
           unsigned short* __restrict__ Cbf, int nrows, int K, int M) {
    constexpr int NW = (BM / 64) * (BN / 64);
    constexpr int WN = BN / 64;
    constexpr int AC = BM / 16, BC = BN / 16;
    constexpr int TC = 2 * (AC + BC);
    constexpr int BUF = TC * 512;  // shorts
    __shared__ unsigned short sm[2 * BUF];
    const int tid = threadIdx.x, l = tid & 63, wid = tid >> 6;
    const int wr = wid / WN, wc = wid % WN;
    const int bm = blockIdx.x * BM, bn = blockIdx.y * BN;
    const int rb0 = blockIdx.x * AC, nb0 = blockIdx.y * BC;
    const int NKB = K >> 5, MB = M >> 4;
    const int fo = (l >> 4) * 128 + (l & 15) * 8;
    f32x4 acc[4][4] = {};

    auto stage = [&](int buf, int kb) {
        unsigned short* base = sm + buf * BUF;
        const unsigned short* ga_h = ah + ((size_t)kb * NRBP + rb0) * 512;
        const unsigned short* ga_l = al + ((size_t)kb * NRBP + rb0) * 512;
        const unsigned short* gb_h = wh + ((size_t)kb * MB + nb0) * 512;
        const unsigned short* gb_l = wl + ((size_t)kb * MB + nb0) * 512;
        for (int q = wid; q < TC; q += NW) {
            const unsigned short* s;
            if (q < AC) s = ga_h + q * 512;
            else if (q < 2 * AC) s = ga_l + (q - AC) * 512;
            else if (q < 2 * AC + BC) s = gb_h + (q - 2 * AC) * 512;
            else s = gb_l + (q - 2 * AC - BC) * 512;
            gll16(base + q * 512, s + l * 8);
        }
    };

    stage(0, 0);
    __syncthreads();
    for (int kb = 0; kb < NKB; ++kb) {
        const int cur = kb & 1;
        if (kb + 1 < NKB) stage(cur ^ 1, kb + 1);
        const unsigned short* base = sm + cur * BUF;
        bf16x8 a_h[4], a_l[4], b_h[4], b_l[4];
#pragma unroll
        for (int i = 0; i < 4; ++i) {
            a_h[i] = *reinterpret_cast<const bf16x8*>(base + (wr * 4 + i) * 512 + fo);
            a_l[i] = *reinterpret_cast<const bf16x8*>(base + (AC + wr * 4 + i) * 512 + fo);
        }
#pragma unroll
        for (int j = 0; j < 4; ++j) {
            b_h[j] = *reinterpret_cast<const bf16x8*>(base + (2 * AC + wc * 4 + j) * 512 + fo);
            b_l[j] = *reinterpret_cast<const bf16x8*>(base + (2 * AC + BC + wc * 4 + j) * 512 + fo);
        }
#pragma unroll
        for (int i = 0; i < 4; ++i)
#pragma unroll
            for (int j = 0; j < 4; ++j) {
                acc[i][j] = __builtin_amdgcn_mfma_f32_16x16x32_bf16(a_h[i], b_h[j], acc[i][j], 0, 0, 0);
                acc[i][j] = __builtin_amdgcn_mfma_f32_16x16x32_bf16(a_h[i], b_l[j], acc[i][j], 0, 0, 0);
                acc[i][j] = __builtin_amdgcn_mfma_f32_16x16x32_bf16(a_l[i], b_h[j], acc[i][j], 0, 0, 0);
            }
        __syncthreads();
    }
#pragma unroll
    for (int j = 0; j < 4; ++j) {
        int col = bn + wc * 64 + j * 16 + (l & 15);
#pragma unroll
        for (int i = 0; i < 4; ++i) {
            int row0 = bm + wr * 64 + i * 16 + (l >> 4) * 4;
#pragma unroll
            for (int r = 0; r < 4; ++r) {
                int row = row0 + r;
                if (row < nrows)
                    Cbf[(size_t)row * M + col] = f2bf_u(acc[i][j][r]);
            }
        }
    }
}

// ---------------- head GEMM (fp32 A, in-kernel split, 3-pass) -------------------
template<int BM, int BN, bool RELU>
__global__ __launch_bounds__((BM / 64) * (BN / 64) * 64)
void k_mm(const float* __restrict__ A, const unsigned short* __restrict__ wh,
          const unsigned short* __restrict__ wl, const float* __restrict__ bias,
          float* __restrict__ Cout, int nrows, int K, int M) {
    constexpr int T = (BM / 64) * (BN / 64) * 64;
    constexpr int WN = BN / 64;
    constexpr int QI = BM * 8 / T;
    __shared__ unsigned short Ah[BM * 32], Al[BM * 32], Bh[BN * 32], Bl[BN * 32];
    int tid = threadIdx.x;
    int l = tid & 63;
    int wid = tid >> 6;
    int wr = wid / WN, wc = wid % WN;
    int bm = blockIdx.x * BM, bn = blockIdx.y * BN;
    int nb0 = bn >> 4;
    f32x4 acc[4][4] = {};
    int fo = (l >> 4) * 128 + (l & 15) * 8;

    for (int k0 = 0; k0 < K; k0 += 32) {
        int kb = k0 >> 5;
#pragma unroll
        for (int q = 0; q < QI; ++q) {
            int t2 = tid + q * T;
            int row = t2 >> 3, kq = t2 & 7;
            int grow = bm + row;
            float4 av = make_float4(0.f, 0.f, 0.f, 0.f);
            if (grow < nrows)
                av = *reinterpret_cast<const float4*>(&A[(size_t)grow * K + k0 + kq * 4]);
            unsigned short h0 = f2bf_u(av.x), h1 = f2bf_u(av.y),
                           h2 = f2bf_u(av.z), h3 = f2bf_u(av.w);
            uint2 hp, lp;
            hp.x = (unsigned)h0 | ((unsigned)h1 << 16);
            hp.y = (unsigned)h2 | ((unsigned)h3 << 16);
            lp.x = (unsigned)f2bf_u(av.x - bfu2f(h0)) | ((unsigned)f2bf_u(av.y - bfu2f(h1)) << 16);
            lp.y = (unsigned)f2bf_u(av.z - bfu2f(h2)) | ((unsigned)f2bf_u(av.w - bfu2f(h3)) << 16);
            int off = (row >> 4) * 512 + (kq >> 1) * 128 + (row & 15) * 8 + (kq & 1) * 4;
            *reinterpret_cast<uint2*>(&Ah[off]) = hp;
            *reinterpret_cast<uint2*>(&Al[off]) = lp;
        }
        const int4* sh = reinterpret_cast<const int4*>(wh) + (size_t)(kb * (M >> 4) + nb0) * 64;
        const int4* sl = reinterpret_cast<const int4*>(wl) + (size_t)(kb * (M >> 4) + nb0) * 64;
        for (int u = tid; u < BN * 4; u += T) {
            *reinterpret_cast<int4*>(&Bh[u * 8]) = sh[u];
            *reinterpret_cast<int4*>(&Bl[u * 8]) = sl[u];
        }
        __syncthreads();
        bf16x8 ah4[4], al4[4], bh4[4], bl4[4];
#pragma unroll
        for (int i = 0; i < 4; ++i) {
            ah4[i] = *reinterpret_cast<const bf16x8*>(&Ah[(wr * 4 + i) * 512 + fo]);
            al4[i] = *reinterpret_cast<const bf16x8*>(&Al[(wr * 4 + i) * 512 + fo]);
        }
#pragma unroll
        for (int j = 0; j < 4; ++j) {
            bh4[j] = *reinterpret_cast<const bf16x8*>(&Bh[(wc * 4 + j) * 512 + fo]);
            bl4[j] = *reinterpret_cast<const bf16x8*>(&Bl[(wc * 4 + j) * 512 + fo]);
        }
#pragma unroll
        for (int i = 0; i < 4; ++i)
#pragma unroll
            for (int j = 0; j < 4; ++j) {
                acc[i][j] = __builtin_amdgcn_mfma_f32_16x16x32_bf16(ah4[i], bh4[j], acc[i][j], 0, 0, 0);
                acc[i][j] = __builtin_amdgcn_mfma_f32_16x16x32_bf16(ah4[i], bl4[j], acc[i][j], 0, 0, 0);
                acc[i][j] = __builtin_amdgcn_mfma_f32_16x16x32_bf16(al4[i], bh4[j], acc[i][j], 0, 0, 0);
            }
        __syncthreads();
    }
#pragma unroll
    for (int j = 0; j < 4; ++j) {
        int col = bn + wc * 64 + j * 16 + (l & 15);
        float bv = bias[col];
#pragma unroll
        for (int i = 0; i < 4; ++i) {
            int row0 = bm + wr * 64 + i * 16 + (l >> 4) * 4;
#pragma unroll
            for (int r = 0; r < 4; ++r) {
                int row = row0 + r;
                if (row < nrows) {
                    float v = acc[i][j][r] + bv;
                    if (RELU) v = fmaxf(v, 0.f);
                    Cout[(size_t)row * M + col] = v;
                }
            }
        }
    }
}

// ---------------- launch ----------------

extern "C" void kernel_launch(void* const* d_in, const int* in_sizes, int n_in,
                              void* d_out, int out_size, void* d_ws, size_t ws_size,
                              hipStream_t stream) {
    const float* x        = (const float*)d_in[0];
    const int*   edge_row = (const int*)d_in[1];
    const int*   edge_col = (const int*)d_in[2];
    const float* edge_val = (const float*)d_in[3];
    const float* W1  = (const float*)d_in[4];
    const float* b1  = (const float*)d_in[5];
    const float* W2  = (const float*)d_in[6];
    const float* b2  = (const float*)d_in[7];
    const float* W3  = (const float*)d_in[8];
    const float* b3  = (const float*)d_in[9];
    const float* P1  = (const float*)d_in[10];
    const float* pb1 = (const float*)d_in[11];
    const float* P2  = (const float*)d_in[12];
    const float* pb2 = (const float*)d_in[13];

    const int N = NN, E = NE;

    uintptr_t p = (uintptr_t)d_ws;
    auto alloc = [&](size_t bytes) -> void* {
        void* r = (void*)p;
        p += (bytes + 255) & ~(size_t)255;
        return r;
    };
    float* dinv   = (float*)alloc((size_t)N * 4);
    int*   rowptr = (int*)alloc((size_t)(N + 1) * 4);
    int*   bcnt   = (int*)alloc(256 * 4);
    int*   boff   = (int*)alloc(256 * 4);
    int*   gcur   = (int*)alloc(256 * 4);
    int2*  etmp   = (int2*)alloc((size_t)E * 8);
    int2*  epk    = (int2*)alloc((size_t)E * 8);
    unsigned short* Hbf = (unsigned short*)alloc((size_t)N * 256 * 2);
    const size_t PLANE = (size_t)8 * NRBP * 512 * 2;  // bytes
    unsigned short* pAh = (unsigned short*)alloc(PLANE);
    unsigned short* pAl = (unsigned short*)alloc(PLANE);
    unsigned short* pBh = (unsigned short*)alloc(PLANE);
    unsigned short* pBl = (unsigned short*)alloc(PLANE);
    float* bufT = (float*)pBh;  // head intermediate aliases pBh (free after GEMM3)
    unsigned short* wf1h = (unsigned short*)alloc(65536 * 2);
    unsigned short* wf1l = (unsigned short*)alloc(65536 * 2);
    unsigned short* wf2h = (unsigned short*)alloc(65536 * 2);
    unsigned short* wf2l = (unsigned short*)alloc(65536 * 2);
    unsigned short* wf3h = (unsigned short*)alloc(32768 * 2);
    unsigned short* wf3l = (unsigned short*)alloc(32768 * 2);
    unsigned short* p1h  = (unsigned short*)alloc(16384 * 2);
    unsigned short* p1l  = (unsigned short*)alloc(16384 * 2);
    unsigned short* p2h  = (unsigned short*)alloc(16384 * 2);
    unsigned short* p2l  = (unsigned short*)alloc(16384 * 2);

    float* emb = (float*)d_out;
    float* z   = (float*)d_out + (size_t)N * 128;

    dim3 b256(256);
    const int gE1k = (E + 1023) / 1024;  // 782

    // weight/x splits (independent)
    k_wsplit<<<dim3(256), b256, 0, stream>>>(W1, wf1h, wf1l, 256, 256);
    k_wsplit<<<dim3(256), b256, 0, stream>>>(W2, wf2h, wf2l, 256, 256);
    k_wsplit<<<dim3(128), b256, 0, stream>>>(W3, wf3h, wf3l, 256, 128);
    k_wsplit<<<dim3(64),  b256, 0, stream>>>(P1, p1h, p1l, 128, 128);
    k_wsplit<<<dim3(64),  b256, 0, stream>>>(P2, p2h, p2l, 128, 128);
    k_xsplit<<<dim3((N * 64 + 255) / 256), b256, 0, stream>>>(x, pAh, pAl, N);

    // CSR build: bucket histogram -> scan -> bucket scatter -> in-bucket sort(+deg)
    hipMemsetAsync(bcnt, 0, 256 * 4, stream);
    k_bhist<<<dim3(gE1k), b256, 0, stream>>>(edge_col, bcnt, E);
    k_bscan<<<dim3(1), b256, 0, stream>>>(bcnt, boff, gcur, rowptr);
    k_bscat<<<dim3(gE1k), b256, 0, stream>>>(edge_row, edge_col, edge_val, gcur, etmp, E);
    k_bsort<<<dim3(NBK), b256, 0, stream>>>(etmp, boff, rowptr, dinv, epk);
    k_normw<<<dim3((E + 255) / 256), b256, 0, stream>>>(epk, dinv, E);

    const int gagg = (N + 3) / 4;  // 12500

    // layer 1: Hbf = x @ W1 ; pB = split(relu(agg(Hbf)*dinv + b1))
    k_mmf<128, 128><<<dim3(391, 2), dim3(256), 0, stream>>>(pAh, pAl, wf1h, wf1l, Hbf, N, 256, 256);
    k_agg<256, true, true><<<dim3(gagg), b256, 0, stream>>>(Hbf, rowptr, epk, dinv, b1, nullptr, pBh, pBl);
    // layer 2
    k_mmf<128, 128><<<dim3(391, 2), dim3(256), 0, stream>>>(pBh, pBl, wf2h, wf2l, Hbf, N, 256, 256);
    k_agg<256, true, true><<<dim3(gagg), b256, 0, stream>>>(Hbf, rowptr, epk, dinv, b2, nullptr, pAh, pAl);
    // layer 3
    k_mmf<64, 128><<<dim3(782, 1), dim3(128), 0, stream>>>(pAh, pAl, wf3h, wf3l, Hbf, N, 256, 128);
    k_agg<128, false, false><<<dim3(gagg), b256, 0, stream>>>(Hbf, rowptr, epk, dinv, b3, emb, nullptr, nullptr);
    // head: z = relu(emb @ P1 + pb1) @ P2 + pb2
    k_mm<64, 128, true ><<<dim3(782, 1), dim3(128), 0, stream>>>(emb, p1h, p1l, pb1, bufT, N, 128, 128);
    k_mm<64, 128, false><<<dim3(782, 1), dim3(128), 0, stream>>>(bufT, p2h, p2l, pb2, z, N, 128, 128);
}